// Round 1
// baseline (472.128 us; speedup 1.0000x reference)
//
#include <hip/hip_runtime.h>
#include <math.h>

#define F 256
#define Hh 128
#define MAXL 3072

typedef short bf16x8 __attribute__((ext_vector_type(8)));
typedef float f32x4 __attribute__((ext_vector_type(4)));
typedef unsigned int uint4v __attribute__((ext_vector_type(4)));

__device__ inline unsigned short f2bf_rne(float f) {
  unsigned u = __float_as_uint(f);
  unsigned r = u + 0x7fff + ((u >> 16) & 1);
  return (unsigned short)(r >> 16);
}
__device__ inline float bf2f(unsigned short h) {
  return __uint_as_float((unsigned)h << 16);
}

// ---------------------------------------------------------------------------
// K0: zero out, prefix-scan lengths, split W1 into bf16 hi/lo transposed
// chunk-major:  whT[chunk][col][k]  (chunk = k/32, k local 0..31), 8 chunks.
// W1 split stays RNE (one-time cost, max precision on the hi term).
// ---------------------------------------------------------------------------
__global__ void init_kernel(const int* __restrict__ lengths, int* __restrict__ offsets,
                            float* __restrict__ out, const float* __restrict__ W1,
                            unsigned short* __restrict__ whT, unsigned short* __restrict__ wlT,
                            int S, int outN) {
  int t = blockIdx.x * blockDim.x + threadIdx.x;
  int stride = gridDim.x * blockDim.x;
  for (int i = t; i < outN; i += stride) out[i] = 0.f;
  for (int i = t; i < F * Hh; i += stride) {
    int k = i >> 7, col = i & 127;
    float v = W1[i];
    unsigned short h = f2bf_rne(v);
    unsigned short l = f2bf_rne(v - bf2f(h));
    int dst = (k >> 5) * (128 * 32) + col * 32 + (k & 31);
    whT[dst] = h;
    wlT[dst] = l;
  }
  if (blockIdx.x == 0) {
    __shared__ int buf[256];
    int tid = threadIdx.x;
    int v = (tid < S) ? lengths[tid] : 0;
    buf[tid] = v;
    __syncthreads();
    for (int o = 1; o < 256; o <<= 1) {
      int add = (tid >= o) ? buf[tid - o] : 0;
      __syncthreads();
      buf[tid] += add;
      __syncthreads();
    }
    if (tid < S) offsets[tid] = buf[tid] - v;   // exclusive
    if (tid == S - 1) offsets[S] = buf[tid];    // total N
  }
}

// ---------------------------------------------------------------------------
// K1: fused MLP via MFMA, no LDS staging, no K-loop barriers.
// THIS ROUND: VGPR diet to get off the 2-waves/SIMD occupancy cliff
// (512-reg file / ~180 VGPR = 2 waves/SIMD -> un-hidden ~700cy x-load
// latency).  Changes vs previous version:
//   - A fragments: 2-deep rt software pipeline (p/q register pairs, 16 VGPR
//     instead of av0[4]/av1[4] = 32), loads for rt+2 issued right after rt
//     is consumed.
//   - x addressing: one base pointer per rt computed ONCE; per-kc offset is
//     kc*128 B which folds into the 13-bit signed immediate of
//     global_load_dwordx4 -> zero per-iteration address VALU.
//   - __launch_bounds__(256, 3) pins >=3 waves/SIMD.
// Numerics unchanged: truncation split hi/lo, 3 MFMA passes (hh+hl+lh).
// ---------------------------------------------------------------------------
#define LOADA(V0, V1, RT) do {                                        \
    V0 = make_float4(0.f, 0.f, 0.f, 0.f);                             \
    V1 = make_float4(0.f, 0.f, 0.f, 0.f);                             \
    if (rv[RT]) {                                                     \
      V0 = *(const float4*)(xb[RT] + kc * 32);                        \
      V1 = *(const float4*)(xb[RT] + kc * 32 + 4);                    \
    }                                                                 \
  } while (0)

#define STEP(V0, V1, RT) do {                                         \
    union { uint4v u; bf16x8 b; } Hu, Lu;                             \
    const float ff[8] = {V0.x, V0.y, V0.z, V0.w,                      \
                         V1.x, V1.y, V1.z, V1.w};                     \
    _Pragma("unroll")                                                 \
    for (int q = 0; q < 4; ++q) {                                     \
      unsigned ua = __float_as_uint(ff[2 * q]);                       \
      unsigned ub = __float_as_uint(ff[2 * q + 1]);                   \
      Hu.u[q] = __builtin_amdgcn_perm(ub, ua, 0x07060302u);           \
      float ra = ff[2 * q]     - __uint_as_float(ua & 0xFFFF0000u);   \
      float rb = ff[2 * q + 1] - __uint_as_float(ub & 0xFFFF0000u);   \
      Lu.u[q] = __builtin_amdgcn_perm(__float_as_uint(rb),            \
                                      __float_as_uint(ra),            \
                                      0x07060302u);                   \
    }                                                                 \
    _Pragma("unroll")                                                 \
    for (int ct = 0; ct < 4; ++ct) {                                  \
      acc[RT][ct] = __builtin_amdgcn_mfma_f32_16x16x32_bf16(          \
          Hu.b, bh[ct], acc[RT][ct], 0, 0, 0);                        \
      acc[RT][ct] = __builtin_amdgcn_mfma_f32_16x16x32_bf16(          \
          Hu.b, bl[ct], acc[RT][ct], 0, 0, 0);                        \
      acc[RT][ct] = __builtin_amdgcn_mfma_f32_16x16x32_bf16(          \
          Lu.b, bh[ct], acc[RT][ct], 0, 0, 0);                        \
    }                                                                 \
  } while (0)

__global__ __launch_bounds__(256, 3) void mlp_kernel(
    const float* __restrict__ x,
    const unsigned short* __restrict__ whT, const unsigned short* __restrict__ wlT,
    const float* __restrict__ b1, const float* __restrict__ W2,
    const float* __restrict__ b2, float* __restrict__ yv,
    float* __restrict__ zv, int N) {
  __shared__ float redy[128][2];
  __shared__ float redz[128][2];

  const int t = threadIdx.x;
  const int lane = t & 63;
  const int w = t >> 6;
  const int wr = w >> 1, wc = w & 1;           // wave grid 2x2
  const int ln15 = lane & 15, lq = lane >> 4;  // quad

  const int row0 = blockIdx.x * 128;

  f32x4 acc[4][4];  // [rt][ct]
#pragma unroll
  for (int i = 0; i < 4; ++i)
#pragma unroll
    for (int j = 0; j < 4; ++j) acc[i][j] = (f32x4){0.f, 0.f, 0.f, 0.f};

  int rowg[4];
  bool rv[4];
  const float* xb[4];
#pragma unroll
  for (int rt = 0; rt < 4; ++rt) {
    rowg[rt] = row0 + wr * 64 + rt * 16 + ln15;
    rv[rt] = rowg[rt] < N;
    xb[rt] = x + (size_t)rowg[rt] * F + lq * 8;   // +kc*32 folds to imm offset
  }
  const int cbase = wc * 64 + ln15;               // + ct*16
  const unsigned short* wb = whT + cbase * 32 + lq * 8;
  const unsigned short* lb = wlT + cbase * 32 + lq * 8;

  for (int kc = 0; kc < 8; ++kc) {
    float4 p0, p1, q0, q1;
    LOADA(p0, p1, 0);
    LOADA(q0, q1, 1);
    bf16x8 bh[4], bl[4];
#pragma unroll
    for (int ct = 0; ct < 4; ++ct) {
      bh[ct] = *(const bf16x8*)(wb + kc * 4096 + ct * 512);
      bl[ct] = *(const bf16x8*)(lb + kc * 4096 + ct * 512);
    }
    STEP(p0, p1, 0);
    LOADA(p0, p1, 2);      // prefetch rt2 into freed p regs
    STEP(q0, q1, 1);
    LOADA(q0, q1, 3);      // prefetch rt3 into freed q regs
    STEP(p0, p1, 2);
    STEP(q0, q1, 3);
  }

  // ---- epilogue: h = tanh(acc + b1), contract with W2 ----
  // acc[rt][ct][rg]: row = wr*64+rt*16+lq*4+rg, col = wc*64+ct*16+ln15
  float yp[4][4], zp[4][4];
#pragma unroll
  for (int i = 0; i < 4; ++i)
#pragma unroll
    for (int j = 0; j < 4; ++j) { yp[i][j] = 0.f; zp[i][j] = 0.f; }
#pragma unroll
  for (int ct = 0; ct < 4; ++ct) {
    int c = cbase + ct * 16;
    float b1c = b1[c], wyc = W2[2 * c], wzc = W2[2 * c + 1];
#pragma unroll
    for (int rt = 0; rt < 4; ++rt)
#pragma unroll
      for (int rg = 0; rg < 4; ++rg) {
        float a = acc[rt][ct][rg] + b1c;
        float e = __expf(2.f * a);
        float h = 1.f - __fdividef(2.f, e + 1.f);   // tanh(a)
        yp[rt][rg] = fmaf(h, wyc, yp[rt][rg]);
        zp[rt][rg] = fmaf(h, wzc, zp[rt][rg]);
      }
  }
#pragma unroll
  for (int rt = 0; rt < 4; ++rt)
#pragma unroll
    for (int rg = 0; rg < 4; ++rg) {
      float vy = yp[rt][rg], vz = zp[rt][rg];
#pragma unroll
      for (int m = 8; m; m >>= 1) {
        vy += __shfl_xor(vy, m);
        vz += __shfl_xor(vz, m);
      }
      if (ln15 == 0) {
        int row = wr * 64 + rt * 16 + lq * 4 + rg;
        redy[row][wc] = vy;
        redz[row][wc] = vz;
      }
    }
  __syncthreads();
  if (t < 128) {
    int g = row0 + t;
    if (g < N) {
      yv[g] = redy[t][0] + redy[t][1] + b2[0];
      zv[g] = redz[t][0] + redz[t][1] + b2[1];
    }
  }
}

#undef LOADA
#undef STEP

// ---------------------------------------------------------------------------
// K2: per-segment stats + attention weights.  One 1024-thread block/segment.
// ---------------------------------------------------------------------------
__device__ inline float wave_reduce_sum(float v) {
#pragma unroll
  for (int o = 32; o; o >>= 1) v += __shfl_down(v, o);
  return v;
}
__device__ inline float wave_reduce_max(float v) {
#pragma unroll
  for (int o = 32; o; o >>= 1) v = fmaxf(v, __shfl_down(v, o));
  return v;
}

__global__ __launch_bounds__(1024) void stats_kernel(
    const float* __restrict__ yv, const float* __restrict__ zv,
    const int* __restrict__ offsets, const int* __restrict__ lengths,
    float* __restrict__ attn) {
  __shared__ float ybuf[MAXL];
  __shared__ float zbuf[MAXL];
  __shared__ float redA[16], redB[16], redC[16];
  const int s = blockIdx.x;
  const int off = offsets[s];
  const int L = lengths[s];
  const int t = threadIdx.x;
  const int lane = t & 63, wid = t >> 6;   // 16 waves

  float lmax = -1e30f;
  for (int i = t; i < L; i += 1024) {
    float yy = yv[off + i];
    ybuf[i] = yy;
    zbuf[i] = zv[off + i];
    lmax = fmaxf(lmax, yy);
  }
  lmax = wave_reduce_max(lmax);
  if (lane == 0) redA[wid] = lmax;
  __syncthreads();
  float ymax = redA[0];
#pragma unroll
  for (int q = 1; q < 16; ++q) ymax = fmaxf(ymax, redA[q]);
  const float invL = 1.f / (float)L;
  __syncthreads();

  float sw = 0.f, smx = 0.f, sz = 0.f;
  for (int i = t; i < L; i += 1024) {
    float wgt = __expf(ybuf[i] - ymax);
    float xp = (float)(i + 1) * invL;
    sw += wgt;
    smx = fmaf(xp, wgt, smx);
    sz += zbuf[i];
  }
  sw = wave_reduce_sum(sw);
  smx = wave_reduce_sum(smx);
  sz = wave_reduce_sum(sz);
  if (lane == 0) { redA[wid] = sw; redB[wid] = smx; redC[wid] = sz; }
  __syncthreads();
  float wsum = 0.f, mxs = 0.f, zsum = 0.f;
#pragma unroll
  for (int q = 0; q < 16; ++q) { wsum += redA[q]; mxs += redB[q]; zsum += redC[q]; }
  const float mu = mxs / wsum;
  const float tz = zsum * invL;
  const float sd = fmaxf(tz, 0.f) + log1pf(__expf(-fabsf(tz)));  // softplus
  const float invsd = 1.f / sd;
  const float C = 0.3989422804014327f;  // 1/sqrt(2*pi)
  __syncthreads();

  float ps = 0.f;
  for (int i = t; i < L; i += 1024) {
    float xp = (float)(i + 1) * invL;
    float u = (xp - mu) * invsd;
    float p = __expf(-0.5f * u * u) * (C * invsd);
    ybuf[i] = p;
    ps += p;
  }
  ps = wave_reduce_sum(ps);
  if (lane == 0) redA[wid] = ps;
  __syncthreads();
  float psum = 0.f;
#pragma unroll
  for (int q = 0; q < 16; ++q) psum += redA[q];
  const float sc = 1.f / (psum + 0.001f);
  for (int i = t; i < L; i += 1024) attn[off + i] = ybuf[i] * sc;
}

// ---------------------------------------------------------------------------
// K3: pooled output.  out[s,f] = sum_i attn_i * x[i,f].
// Grid (S, 32 chunks); 4 waves/block; wave = one row per iter, lane = float4
// of features (1KB/wave fully coalesced).  2 chains for ILP.
// ---------------------------------------------------------------------------
__global__ __launch_bounds__(256) void pool_kernel(
    const float* __restrict__ x, const float* __restrict__ attn,
    const int* __restrict__ offsets, const int* __restrict__ lengths,
    float* __restrict__ out, int nchunks) {
  __shared__ float4 sbuf[4][64];
  const int s = blockIdx.x, c = blockIdx.y;
  const int off = offsets[s], L = lengths[s];
  const int i0 = (int)((long long)L * c / nchunks);
  const int i1 = (int)((long long)L * (c + 1) / nchunks);
  const int t = threadIdx.x;
  const int lane = t & 63, wid = t >> 6;

  float4 a0 = make_float4(0.f, 0.f, 0.f, 0.f);
  float4 a1 = make_float4(0.f, 0.f, 0.f, 0.f);
  int i = i0 + wid;
  for (; i + 4 < i1; i += 8) {
    float w0 = attn[off + i];
    float w1 = attn[off + i + 4];
    float4 v0 = *(const float4*)&x[(size_t)(off + i) * F + lane * 4];
    float4 v1 = *(const float4*)&x[(size_t)(off + i + 4) * F + lane * 4];
    a0.x = fmaf(w0, v0.x, a0.x); a0.y = fmaf(w0, v0.y, a0.y);
    a0.z = fmaf(w0, v0.z, a0.z); a0.w = fmaf(w0, v0.w, a0.w);
    a1.x = fmaf(w1, v1.x, a1.x); a1.y = fmaf(w1, v1.y, a1.y);
    a1.z = fmaf(w1, v1.z, a1.z); a1.w = fmaf(w1, v1.w, a1.w);
  }
  if (i < i1) {
    float w0 = attn[off + i];
    float4 v0 = *(const float4*)&x[(size_t)(off + i) * F + lane * 4];
    a0.x = fmaf(w0, v0.x, a0.x); a0.y = fmaf(w0, v0.y, a0.y);
    a0.z = fmaf(w0, v0.z, a0.z); a0.w = fmaf(w0, v0.w, a0.w);
  }
  a0.x += a1.x; a0.y += a1.y; a0.z += a1.z; a0.w += a1.w;
  sbuf[wid][lane] = a0;
  __syncthreads();
  if (wid == 0) {
    float4 r0 = sbuf[0][lane], r1 = sbuf[1][lane];
    float4 r2 = sbuf[2][lane], r3 = sbuf[3][lane];
    float rx = (r0.x + r1.x) + (r2.x + r3.x);
    float ry = (r0.y + r1.y) + (r2.y + r3.y);
    float rz = (r0.z + r1.z) + (r2.z + r3.z);
    float rw = (r0.w + r1.w) + (r2.w + r3.w);
    float* o = &out[s * F + lane * 4];
    atomicAdd(o + 0, rx);
    atomicAdd(o + 1, ry);
    atomicAdd(o + 2, rz);
    atomicAdd(o + 3, rw);
  }
}

// ---------------------------------------------------------------------------
extern "C" void kernel_launch(void* const* d_in, const int* in_sizes, int n_in,
                              void* d_out, int out_size, void* d_ws, size_t ws_size,
                              hipStream_t stream) {
  const float* x      = (const float*)d_in[0];
  const int* lengths  = (const int*)d_in[1];
  const float* W1     = (const float*)d_in[2];
  const float* b1     = (const float*)d_in[3];
  const float* W2     = (const float*)d_in[4];
  const float* b2     = (const float*)d_in[5];
  const int S = in_sizes[1];
  const int N = in_sizes[0] / F;

  float* out  = (float*)d_out;             // S*F
  float* attn = out + (size_t)S * F;       // N

  int*   offsets = (int*)d_ws;                       // 512 ints (2 KB)
  float* yv = (float*)d_ws + 512;                    // N floats
  float* zv = yv + N;                                // N floats
  unsigned short* whT = (unsigned short*)(zv + N);   // 32768 shorts (64 KB)
  unsigned short* wlT = whT + F * Hh;                // 32768 shorts (64 KB)

  init_kernel<<<64, 256, 0, stream>>>(lengths, offsets, out, W1, whT, wlT, S, S * F);
  mlp_kernel<<<(N + 127) / 128, 256, 0, stream>>>(x, whT, wlT, b1, W2, b2, yv, zv, N);
  stats_kernel<<<S, 1024, 0, stream>>>(yv, zv, offsets, lengths, attn);
  pool_kernel<<<dim3(S, 32), 256, 0, stream>>>(x, attn, offsets, lengths, out, 32);
}

// Round 2
// 453.716 us; speedup vs baseline: 1.0406x; 1.0406x over previous
//
#include <hip/hip_runtime.h>
#include <math.h>

#define F 256
#define Hh 128
#define MAXL 3072

typedef short bf16x8 __attribute__((ext_vector_type(8)));
typedef float f32x4 __attribute__((ext_vector_type(4)));
typedef unsigned int uint4v __attribute__((ext_vector_type(4)));

__device__ inline unsigned short f2bf_rne(float f) {
  unsigned u = __float_as_uint(f);
  unsigned r = u + 0x7fff + ((u >> 16) & 1);
  return (unsigned short)(r >> 16);
}
__device__ inline float bf2f(unsigned short h) {
  return __uint_as_float((unsigned)h << 16);
}

// ---------------------------------------------------------------------------
// K0: zero out, prefix-scan lengths, split W1 into bf16 hi/lo transposed
// chunk-major:  whT[chunk][col][k]  (chunk = k/32, k local 0..31), 8 chunks.
// ---------------------------------------------------------------------------
__global__ void init_kernel(const int* __restrict__ lengths, int* __restrict__ offsets,
                            float* __restrict__ out, const float* __restrict__ W1,
                            unsigned short* __restrict__ whT, unsigned short* __restrict__ wlT,
                            int S, int outN) {
  int t = blockIdx.x * blockDim.x + threadIdx.x;
  int stride = gridDim.x * blockDim.x;
  for (int i = t; i < outN; i += stride) out[i] = 0.f;
  for (int i = t; i < F * Hh; i += stride) {
    int k = i >> 7, col = i & 127;
    float v = W1[i];
    unsigned short h = f2bf_rne(v);
    unsigned short l = f2bf_rne(v - bf2f(h));
    int dst = (k >> 5) * (128 * 32) + col * 32 + (k & 31);
    whT[dst] = h;
    wlT[dst] = l;
  }
  if (blockIdx.x == 0) {
    __shared__ int buf[256];
    int tid = threadIdx.x;
    int v = (tid < S) ? lengths[tid] : 0;
    buf[tid] = v;
    __syncthreads();
    for (int o = 1; o < 256; o <<= 1) {
      int add = (tid >= o) ? buf[tid - o] : 0;
      __syncthreads();
      buf[tid] += add;
      __syncthreads();
    }
    if (tid < S) offsets[tid] = buf[tid] - v;   // exclusive
    if (tid == S - 1) offsets[S] = buf[tid];    // total N
  }
}

// ---------------------------------------------------------------------------
// K1: fused MLP via MFMA — ROUND-0 FORM (reverted).  Round-1's 2-deep
// pipeline + __launch_bounds__(256,3) pin regressed +12us (suspected
// spills at the 170-VGPR cliff); this form measured 459.6 in context.
// ---------------------------------------------------------------------------
__global__ __launch_bounds__(256) void mlp_kernel(
    const float* __restrict__ x,
    const unsigned short* __restrict__ whT, const unsigned short* __restrict__ wlT,
    const float* __restrict__ b1, const float* __restrict__ W2,
    const float* __restrict__ b2, float* __restrict__ yv,
    float* __restrict__ zv, int N) {
  __shared__ float redy[128][2];
  __shared__ float redz[128][2];

  const int t = threadIdx.x;
  const int lane = t & 63;
  const int w = t >> 6;
  const int wr = w >> 1, wc = w & 1;           // wave grid 2x2
  const int ln15 = lane & 15, lq = lane >> 4;  // quad

  const int row0 = blockIdx.x * 128;

  f32x4 acc[4][4];  // [rt][ct]
#pragma unroll
  for (int i = 0; i < 4; ++i)
#pragma unroll
    for (int j = 0; j < 4; ++j) acc[i][j] = (f32x4){0.f, 0.f, 0.f, 0.f};

  int rowg[4];
  bool rv[4];
#pragma unroll
  for (int rt = 0; rt < 4; ++rt) {
    rowg[rt] = row0 + wr * 64 + rt * 16 + ln15;
    rv[rt] = rowg[rt] < N;
  }
  const int cbase = wc * 64 + ln15;            // + ct*16

  for (int kc = 0; kc < 8; ++kc) {
    // ---- issue all global loads for this chunk first ----
    float4 av0[4], av1[4];
#pragma unroll
    for (int rt = 0; rt < 4; ++rt) {
      av0[rt] = make_float4(0.f, 0.f, 0.f, 0.f);
      av1[rt] = make_float4(0.f, 0.f, 0.f, 0.f);
      if (rv[rt]) {
        const float* p = &x[(size_t)rowg[rt] * F + kc * 32 + lq * 8];
        av0[rt] = *(const float4*)p;
        av1[rt] = *(const float4*)(p + 4);
      }
    }
    bf16x8 bh[4], bl[4];
#pragma unroll
    for (int ct = 0; ct < 4; ++ct) {
      int o = kc * 4096 + (cbase + ct * 16) * 32 + lq * 8;
      bh[ct] = *(const bf16x8*)&whT[o];
      bl[ct] = *(const bf16x8*)&wlT[o];
    }
    // ---- cheap truncation split + MFMA ----
#pragma unroll
    for (int rt = 0; rt < 4; ++rt) {
      float f[8] = {av0[rt].x, av0[rt].y, av0[rt].z, av0[rt].w,
                    av1[rt].x, av1[rt].y, av1[rt].z, av1[rt].w};
      union { uint4v u; bf16x8 b; } ah, al;
#pragma unroll
      for (int q = 0; q < 4; ++q) {
        unsigned ua = __float_as_uint(f[2 * q]);
        unsigned ub = __float_as_uint(f[2 * q + 1]);
        // hi = upper-16 truncation, packed pairwise
        ah.u[q] = __builtin_amdgcn_perm(ub, ua, 0x07060302u);
        // exact residual, then truncate-pack
        float ra = f[2 * q]     - __uint_as_float(ua & 0xFFFF0000u);
        float rb = f[2 * q + 1] - __uint_as_float(ub & 0xFFFF0000u);
        al.u[q] = __builtin_amdgcn_perm(__float_as_uint(rb), __float_as_uint(ra), 0x07060302u);
      }
#pragma unroll
      for (int ct = 0; ct < 4; ++ct) {
        acc[rt][ct] = __builtin_amdgcn_mfma_f32_16x16x32_bf16(ah.b, bh[ct], acc[rt][ct], 0, 0, 0);
        acc[rt][ct] = __builtin_amdgcn_mfma_f32_16x16x32_bf16(ah.b, bl[ct], acc[rt][ct], 0, 0, 0);
        acc[rt][ct] = __builtin_amdgcn_mfma_f32_16x16x32_bf16(al.b, bh[ct], acc[rt][ct], 0, 0, 0);
      }
    }
  }

  // ---- epilogue: h = tanh(acc + b1), contract with W2 ----
  // acc[rt][ct][rg]: row = wr*64+rt*16+lq*4+rg, col = wc*64+ct*16+ln15
  float yp[4][4], zp[4][4];
#pragma unroll
  for (int i = 0; i < 4; ++i)
#pragma unroll
    for (int j = 0; j < 4; ++j) { yp[i][j] = 0.f; zp[i][j] = 0.f; }
#pragma unroll
  for (int ct = 0; ct < 4; ++ct) {
    int c = cbase + ct * 16;
    float b1c = b1[c], wyc = W2[2 * c], wzc = W2[2 * c + 1];
#pragma unroll
    for (int rt = 0; rt < 4; ++rt)
#pragma unroll
      for (int rg = 0; rg < 4; ++rg) {
        float a = acc[rt][ct][rg] + b1c;
        float e = __expf(2.f * a);
        float h = 1.f - __fdividef(2.f, e + 1.f);   // tanh(a)
        yp[rt][rg] = fmaf(h, wyc, yp[rt][rg]);
        zp[rt][rg] = fmaf(h, wzc, zp[rt][rg]);
      }
  }
#pragma unroll
  for (int rt = 0; rt < 4; ++rt)
#pragma unroll
    for (int rg = 0; rg < 4; ++rg) {
      float vy = yp[rt][rg], vz = zp[rt][rg];
#pragma unroll
      for (int m = 8; m; m >>= 1) {
        vy += __shfl_xor(vy, m);
        vz += __shfl_xor(vz, m);
      }
      if (ln15 == 0) {
        int row = wr * 64 + rt * 16 + lq * 4 + rg;
        redy[row][wc] = vy;
        redz[row][wc] = vz;
      }
    }
  __syncthreads();
  if (t < 128) {
    int g = row0 + t;
    if (g < N) {
      yv[g] = redy[t][0] + redy[t][1] + b2[0];
      zv[g] = redz[t][0] + redz[t][1] + b2[1];
    }
  }
}

// ---------------------------------------------------------------------------
// K2: per-segment stats + attention weights.  One 1024-thread block/segment.
// ---------------------------------------------------------------------------
__device__ inline float wave_reduce_sum(float v) {
#pragma unroll
  for (int o = 32; o; o >>= 1) v += __shfl_down(v, o);
  return v;
}
__device__ inline float wave_reduce_max(float v) {
#pragma unroll
  for (int o = 32; o; o >>= 1) v = fmaxf(v, __shfl_down(v, o));
  return v;
}

__global__ __launch_bounds__(1024) void stats_kernel(
    const float* __restrict__ yv, const float* __restrict__ zv,
    const int* __restrict__ offsets, const int* __restrict__ lengths,
    float* __restrict__ attn) {
  __shared__ float ybuf[MAXL];
  __shared__ float zbuf[MAXL];
  __shared__ float redA[16], redB[16], redC[16];
  const int s = blockIdx.x;
  const int off = offsets[s];
  const int L = lengths[s];
  const int t = threadIdx.x;
  const int lane = t & 63, wid = t >> 6;   // 16 waves

  float lmax = -1e30f;
  for (int i = t; i < L; i += 1024) {
    float yy = yv[off + i];
    ybuf[i] = yy;
    zbuf[i] = zv[off + i];
    lmax = fmaxf(lmax, yy);
  }
  lmax = wave_reduce_max(lmax);
  if (lane == 0) redA[wid] = lmax;
  __syncthreads();
  float ymax = redA[0];
#pragma unroll
  for (int q = 1; q < 16; ++q) ymax = fmaxf(ymax, redA[q]);
  const float invL = 1.f / (float)L;
  __syncthreads();

  float sw = 0.f, smx = 0.f, sz = 0.f;
  for (int i = t; i < L; i += 1024) {
    float wgt = __expf(ybuf[i] - ymax);
    float xp = (float)(i + 1) * invL;
    sw += wgt;
    smx = fmaf(xp, wgt, smx);
    sz += zbuf[i];
  }
  sw = wave_reduce_sum(sw);
  smx = wave_reduce_sum(smx);
  sz = wave_reduce_sum(sz);
  if (lane == 0) { redA[wid] = sw; redB[wid] = smx; redC[wid] = sz; }
  __syncthreads();
  float wsum = 0.f, mxs = 0.f, zsum = 0.f;
#pragma unroll
  for (int q = 0; q < 16; ++q) { wsum += redA[q]; mxs += redB[q]; zsum += redC[q]; }
  const float mu = mxs / wsum;
  const float tz = zsum * invL;
  const float sd = fmaxf(tz, 0.f) + log1pf(__expf(-fabsf(tz)));  // softplus
  const float invsd = 1.f / sd;
  const float C = 0.3989422804014327f;  // 1/sqrt(2*pi)
  __syncthreads();

  float ps = 0.f;
  for (int i = t; i < L; i += 1024) {
    float xp = (float)(i + 1) * invL;
    float u = (xp - mu) * invsd;
    float p = __expf(-0.5f * u * u) * (C * invsd);
    ybuf[i] = p;
    ps += p;
  }
  ps = wave_reduce_sum(ps);
  if (lane == 0) redA[wid] = ps;
  __syncthreads();
  float psum = 0.f;
#pragma unroll
  for (int q = 0; q < 16; ++q) psum += redA[q];
  const float sc = 1.f / (psum + 0.001f);
  for (int i = t; i < L; i += 1024) attn[off + i] = ybuf[i] * sc;
}

// ---------------------------------------------------------------------------
// K3: pooled output.  out[s,f] = sum_i attn_i * x[i,f].
// THIS ROUND: L3-harvest ordering.  mlp streamed x forward, so at pool
// launch the LAST ~256 MiB of x sit in Infinity Cache (x is 268 MB).
// Forward reading is the LRU worst case (every line evicted right before
// use).  We read x in approximate REVERSE stream order instead:
//   grid (32, S) with blockIdx.x = chunk (fast), blockIdx.y = segment;
//   s = S-1-by, c = nchunks-1-bx  -> earliest-dispatched blocks cover the
//   highest global row indices; rows iterate DESCENDING within each wave.
// Pool's own fetches then only evict already-consumed lines; expected HBM
// fetch drops ~268 MB -> ~30-50 MB and the kernel runs at L3 bandwidth.
// ---------------------------------------------------------------------------
__global__ __launch_bounds__(256) void pool_kernel(
    const float* __restrict__ x, const float* __restrict__ attn,
    const int* __restrict__ offsets, const int* __restrict__ lengths,
    float* __restrict__ out, int nchunks, int S) {
  __shared__ float4 sbuf[4][64];
  const int s = S - 1 - blockIdx.y;
  const int c = nchunks - 1 - blockIdx.x;
  const int off = offsets[s], L = lengths[s];
  const int i0 = (int)((long long)L * c / nchunks);
  const int i1 = (int)((long long)L * (c + 1) / nchunks);
  const int t = threadIdx.x;
  const int lane = t & 63, wid = t >> 6;

  float4 a0 = make_float4(0.f, 0.f, 0.f, 0.f);
  float4 a1 = make_float4(0.f, 0.f, 0.f, 0.f);
  int i = i1 - 1 - wid;                       // descending rows
  for (; i - 4 >= i0; i -= 8) {
    float w0 = attn[off + i];
    float w1 = attn[off + i - 4];
    float4 v0 = *(const float4*)&x[(size_t)(off + i) * F + lane * 4];
    float4 v1 = *(const float4*)&x[(size_t)(off + i - 4) * F + lane * 4];
    a0.x = fmaf(w0, v0.x, a0.x); a0.y = fmaf(w0, v0.y, a0.y);
    a0.z = fmaf(w0, v0.z, a0.z); a0.w = fmaf(w0, v0.w, a0.w);
    a1.x = fmaf(w1, v1.x, a1.x); a1.y = fmaf(w1, v1.y, a1.y);
    a1.z = fmaf(w1, v1.z, a1.z); a1.w = fmaf(w1, v1.w, a1.w);
  }
  if (i >= i0) {
    float w0 = attn[off + i];
    float4 v0 = *(const float4*)&x[(size_t)(off + i) * F + lane * 4];
    a0.x = fmaf(w0, v0.x, a0.x); a0.y = fmaf(w0, v0.y, a0.y);
    a0.z = fmaf(w0, v0.z, a0.z); a0.w = fmaf(w0, v0.w, a0.w);
  }
  a0.x += a1.x; a0.y += a1.y; a0.z += a1.z; a0.w += a1.w;
  sbuf[wid][lane] = a0;
  __syncthreads();
  if (wid == 0) {
    float4 r0 = sbuf[0][lane], r1 = sbuf[1][lane];
    float4 r2 = sbuf[2][lane], r3 = sbuf[3][lane];
    float rx = (r0.x + r1.x) + (r2.x + r3.x);
    float ry = (r0.y + r1.y) + (r2.y + r3.y);
    float rz = (r0.z + r1.z) + (r2.z + r3.z);
    float rw = (r0.w + r1.w) + (r2.w + r3.w);
    float* o = &out[s * F + lane * 4];
    atomicAdd(o + 0, rx);
    atomicAdd(o + 1, ry);
    atomicAdd(o + 2, rz);
    atomicAdd(o + 3, rw);
  }
}

// ---------------------------------------------------------------------------
extern "C" void kernel_launch(void* const* d_in, const int* in_sizes, int n_in,
                              void* d_out, int out_size, void* d_ws, size_t ws_size,
                              hipStream_t stream) {
  const float* x      = (const float*)d_in[0];
  const int* lengths  = (const int*)d_in[1];
  const float* W1     = (const float*)d_in[2];
  const float* b1     = (const float*)d_in[3];
  const float* W2     = (const float*)d_in[4];
  const float* b2     = (const float*)d_in[5];
  const int S = in_sizes[1];
  const int N = in_sizes[0] / F;

  float* out  = (float*)d_out;             // S*F
  float* attn = out + (size_t)S * F;       // N

  int*   offsets = (int*)d_ws;                       // 512 ints (2 KB)
  float* yv = (float*)d_ws + 512;                    // N floats
  float* zv = yv + N;                                // N floats
  unsigned short* whT = (unsigned short*)(zv + N);   // 32768 shorts (64 KB)
  unsigned short* wlT = whT + F * Hh;                // 32768 shorts (64 KB)

  init_kernel<<<64, 256, 0, stream>>>(lengths, offsets, out, W1, whT, wlT, S, S * F);
  mlp_kernel<<<(N + 127) / 128, 256, 0, stream>>>(x, whT, wlT, b1, W2, b2, yv, zv, N);
  stats_kernel<<<S, 1024, 0, stream>>>(yv, zv, offsets, lengths, attn);
  pool_kernel<<<dim3(32, S), 256, 0, stream>>>(x, attn, offsets, lengths, out, 32, S);
}